// Round 8
// baseline (263.058 us; speedup 1.0000x reference)
//
#include <hip/hip_runtime.h>

// InstantNGP hash-grid forward, fp32 — corner-per-lane + scalar-path coords.
//
// Structure (R6, validated): 8 lanes per (point, level), one corner per lane,
// dx = lane bit 0 (dx-pairs share a 64B line 75% on linear levels; duplicate
// slots at l>=12 dedup via wave same-address broadcast). 8-lane shfl_xor
// butterfly reduces the corners; lane c==0 stores the float4.
//
// Bottleneck model (fit R1/R2/R6/R7, ±3%): dur = lines/pt × ~3.0 cy/line/CU,
// invariant to cache residency (R2: L2-fit neutral; R7: sc0 L1-bypass exactly
// neutral). Only lever left: line count. This round moves the wave-uniform
// coord loads (6 lines/pt) to the scalar SMEM path via readfirstlane
// -> ~100 lines/pt, predicted ~244 µs. Hash levels (72 lines/pt) are the
// irreducible 72% of the floor.
//
// Level constants (verified vs reference _level_consts(), HW-validated):
//   res = 16<<l ; mask = (1<<min(12+3l,19))-1
//   l 0-2  : linear, strides [1, res, res^2]
//   l 3-11 : hash (primes 1, 2654435761, 805459861)
//   l 12-15: linear, strides [1, res, 0]  (uint32 wrap in ref stride loop)

static constexpr int N_PTS = 500000;

typedef float f4 __attribute__((ext_vector_type(4)));

__global__ __launch_bounds__(256) void hashgrid_fwd(
    const float* __restrict__ coords,   // [N,3]
    const float* __restrict__ table,    // [T,4]
    float* __restrict__ out)            // [N,64]
{
    const unsigned tid = threadIdx.x;
    const unsigned p = tid >> 7;          // local point (0..1) — wave-uniform
    const unsigned l = (tid >> 3) & 15u;  // level
    const unsigned c = tid & 7u;          // corner
    const unsigned dx = c & 1u;
    const unsigned dy = (c >> 1) & 1u;
    const unsigned dz = c >> 2;

    const unsigned n = blockIdx.x * 2u + p;

    // n is wave-uniform; readfirstlane lets the compiler prove it and issue
    // the coord loads as s_load (scalar cache, lgkmcnt) — off the TA pipe.
    const unsigned nu = __builtin_amdgcn_readfirstlane(n);
    const float* cp = coords + (size_t)nu * 3u;
    const float cx = cp[0];
    const float cy = cp[1];
    const float cz = cp[2];

    const unsigned res = 16u << l;
    const float scale = (float)(res - 1u);

    // pos = c*scale + 0.5, no fma contraction (match np fp32 floor boundaries)
    const float px = __fadd_rn(__fmul_rn(cx, scale), 0.5f);
    const float py = __fadd_rn(__fmul_rn(cy, scale), 0.5f);
    const float pz = __fadd_rn(__fmul_rn(cz, scale), 0.5f);
    const float bxf = floorf(px), byf = floorf(py), bzf = floorf(pz);
    const float fx = __fsub_rn(px, bxf);
    const float fy = __fsub_rn(py, byf);
    const float fz = __fsub_rn(pz, bzf);
    const unsigned x = (unsigned)(int)bxf + dx;
    const unsigned y = (unsigned)(int)byf + dy;
    const unsigned z = (unsigned)(int)bzf + dz;

    const unsigned mask = (l >= 3u) ? 0x7FFFFu : ((1u << (12u + 3u * l)) - 1u);

    // this lane's trilinear weight, product order matches np.prod (x*y*z)
    const float wx = dx ? fx : (1.0f - fx);
    const float wy = dy ? fy : (1.0f - fy);
    const float wz = dz ? fz : (1.0f - fz);
    const float w = wx * wy * wz;

    unsigned slot;
    if (l >= 3u && l < 12u) {           // hash levels
        slot = (x ^ (y * 2654435761u) ^ (z * 805459861u)) & mask;
    } else {                            // linear levels
        const unsigned zs = (l < 3u) ? res * res : 0u;   // l>=12: z-stride 0
        slot = (x + y * res + z * zs) & mask;            // uint32 wrap = ref
    }

    const f4 e = *(const f4*)(table + (size_t)slot * 4u);
    float r0 = w * e.x;
    float r1 = w * e.y;
    float r2 = w * e.z;
    float r3 = w * e.w;

    // butterfly reduce over the 8 corner lanes (VALU/DS pipe — hidden)
    #pragma unroll
    for (int m = 1; m <= 4; m <<= 1) {
        r0 += __shfl_xor(r0, m, 64);
        r1 += __shfl_xor(r1, m, 64);
        r2 += __shfl_xor(r2, m, 64);
        r3 += __shfl_xor(r3, m, 64);
    }

    if (c == 0u) {
        f4 o; o.x = r0; o.y = r1; o.z = r2; o.w = r3;
        __builtin_nontemporal_store(o, (f4*)(out + (size_t)n * 64u + (size_t)l * 4u));
    }
}

extern "C" void kernel_launch(void* const* d_in, const int* in_sizes, int n_in,
                              void* d_out, int out_size, void* d_ws, size_t ws_size,
                              hipStream_t stream) {
    const float* coords = (const float*)d_in[0];
    const float* table  = (const float*)d_in[1];
    float* out = (float*)d_out;

    const int blocks = N_PTS / 2;   // 2 points per 256-thread block
    hipLaunchKernelGGL(hashgrid_fwd, dim3(blocks), dim3(256), 0, stream,
                       coords, table, out);
}